// Round 6
// baseline (2216.696 us; speedup 1.0000x reference)
//
#include <hip/hip_runtime.h>
#include <math.h>

// Problem constants
constexpr int DD    = 512;
constexpr int D2    = 1024;
constexpr int NTOK  = 256;
constexpr int NSYM  = 512;
constexpr int NCON  = 64;
constexpr int VOCAB = 256;
constexpr int BS_TOT = 16384;
constexpr int NDEPTH = 6;
constexpr int NLOOK  = 3;
constexpr int BLOCK = 512;
constexpr int SPLIT = 4;           // same as round-4 (bitwise partial sums)
constexpr int KB    = D2 / SPLIT;  // 256
constexpr int LDT   = 68;
constexpr float EPSF = 1e-8f;
constexpr float SCALE = 0.044194173824159216f; // 512^-0.5

struct Params {
    const int* x;
    const float *mag, *phase, *Wr, *Wi, *qw, *qb, *kw, *kb, *vw, *vb, *dec_w, *dec_b, *sym, *con;
    float* out;
    float *bufA, *bufB, *Kmem, *Vmem, *rows, *CW, *qwT, *KVT, *symT, *decT, *conT;
    float *cellP, *QP, *symP, *kvP, *decP, *snorm, *conf, *symErr, *conErr;
    int* hist;
    unsigned* bar;
};

__device__ __forceinline__ void fma4(float4& a, const float4& w, float s) {
    a.x += w.x * s; a.y += w.y * s; a.z += w.z * s; a.w += w.w * s;
}

// Hand-rolled grid barrier: monotonic counter, explicit agent-scope fences.
// Requires all gridDim.x blocks co-resident (host clamps grid via occupancy query).
__device__ __forceinline__ void gbar(unsigned* bar, unsigned target) {
    __syncthreads();
    if (threadIdx.x == 0) {
        __threadfence();   // release: my stores visible at device scope
        __hip_atomic_fetch_add(bar, 1u, __ATOMIC_ACQ_REL, __HIP_MEMORY_SCOPE_AGENT);
        while (__hip_atomic_load(bar, __ATOMIC_ACQUIRE, __HIP_MEMORY_SCOPE_AGENT) < target)
            __builtin_amdgcn_s_sleep(2);
        __threadfence();   // acquire: see others' stores
    }
    __syncthreads();
}

// Tiled GEMM: P[s][t][j] = sum_{k in slice s} X[t][k]*WT[k][j].
// 64j x 64t tile, 512 threads: 2 rows x 4 cols per thread. k ascending ->
// per-output FP chain identical to round-4's gemm64.
__device__ void gemm_tiles(const float* __restrict__ WT, const float* __restrict__ X,
                           float* __restrict__ Pout, int N, int njt,
                           int bid, int gdim, int tid, float* sX, float* sW) {
    int total = njt * 4 * SPLIT;
    int jq = tid & 15;        // 4-col group
    int tq = tid >> 4;        // 0..31, 2-row group
    for (int tile = bid; tile < total; tile += gdim) {
        int jt = tile % njt;
        int r  = tile / njt;
        int tt = r & 3;
        int s  = r >> 2;
        int j0 = jt * 64, t0 = tt * 64, k0 = s * KB;
        float4 a0 = {0,0,0,0}, a1 = {0,0,0,0};
        for (int kc = 0; kc < KB / 32; ++kc) {
            int kbase = k0 + kc * 32;
            __syncthreads();
            {   // X tile: 512 float4s, one per thread, transposed to [k][t]
                int t = tid >> 3, kq = tid & 7;
                float4 v = *(const float4*)&X[(size_t)(t0 + t) * D2 + kbase + kq * 4];
                sX[(kq * 4 + 0) * LDT + t] = v.x;
                sX[(kq * 4 + 1) * LDT + t] = v.y;
                sX[(kq * 4 + 2) * LDT + t] = v.z;
                sX[(kq * 4 + 3) * LDT + t] = v.w;
                // W tile: 32k x 64j
                int kw_ = tid >> 4, j4 = tid & 15;
                *(float4*)&sW[kw_ * LDT + j4 * 4] =
                    *(const float4*)&WT[(size_t)(kbase + kw_) * N + j0 + j4 * 4];
            }
            __syncthreads();
#pragma unroll 8
            for (int k = 0; k < 32; ++k) {
                float x0 = sX[k * LDT + tq * 2];
                float x1 = sX[k * LDT + tq * 2 + 1];
                float4 wb = *(const float4*)&sW[k * LDT + jq * 4];
                fma4(a0, wb, x0);
                fma4(a1, wb, x1);
            }
        }
        size_t base = ((size_t)s * NTOK + (t0 + tq * 2)) * N + j0 + jq * 4;
        *(float4*)&Pout[base]     = a0;
        *(float4*)&Pout[base + N] = a1;
    }
}

__device__ void transpose_tiles(const float* __restrict__ in, float* __restrict__ outp,
                                int R, int C, int ldo, int bid, int gdim, int tid, float* sm) {
    int tcx = C >> 5, total = tcx * (R >> 5);
    float (*t)[33] = (float(*)[33])sm;
    int xx = tid & 31, yy = tid >> 5;   // yy 0..15
    for (int tile = bid; tile < total; tile += gdim) {
        int c0 = (tile % tcx) * 32, r0 = (tile / tcx) * 32;
        __syncthreads();
#pragma unroll
        for (int i = 0; i < 32; i += 16)
            t[yy + i][xx] = in[(size_t)(r0 + yy + i) * C + c0 + xx];
        __syncthreads();
#pragma unroll
        for (int i = 0; i < 32; i += 16)
            outp[(size_t)(c0 + yy + i) * ldo + r0 + xx] = t[xx][yy + i];
    }
}

__device__ void buildcw(const float* __restrict__ Wr, const float* __restrict__ Wi,
                        float* __restrict__ CW, int bid, int gdim, int tid, float* sm) {
    float (*tr)[33] = (float(*)[33])sm;
    float (*ti)[33] = (float(*)[33])(sm + 1056);
    int xx = tid & 31, yy = tid >> 5;
    for (int tile = bid; tile < 256; tile += gdim) {
        int j0 = (tile & 15) * 32, k0 = (tile >> 4) * 32;
        __syncthreads();
#pragma unroll
        for (int i = 0; i < 32; i += 16) {
            tr[yy + i][xx] = Wr[(size_t)(j0 + yy + i) * DD + k0 + xx];
            ti[yy + i][xx] = Wi[(size_t)(j0 + yy + i) * DD + k0 + xx];
        }
        __syncthreads();
#pragma unroll
        for (int i = 0; i < 32; i += 16) {
            float vr = tr[xx][yy + i], vi = ti[xx][yy + i];
            int k = k0 + yy + i, j = j0 + xx;
            CW[(size_t)k * D2 + j]             = vr;
            CW[(size_t)k * D2 + DD + j]        = vi;
            CW[(size_t)(DD + k) * D2 + j]      = -vi;
            CW[(size_t)(DD + k) * D2 + DD + j] = vr;
        }
    }
}

// cellepi: element-wise, j = tid (bitwise = round-4 cellepi_kernel)
__device__ void cellepi_stage(const float* __restrict__ P, float* __restrict__ z,
                              int bid, int gdim, int tid) {
    for (int t = bid; t < NTOK; t += gdim) {
        int j = tid;
        float lr = 0.f, li = 0.f;
#pragma unroll
        for (int s = 0; s < SPLIT; ++s) {
            lr += P[((size_t)s * NTOK + t) * D2 + j];
            li += P[((size_t)s * NTOK + t) * D2 + DD + j];
        }
        float m = sqrtf(lr * lr + li * li + EPSF);
        float inv = 1.0f / (1.0f + m);
        z[(size_t)t * D2 + j]      = tanhf(lr * inv);
        z[(size_t)t * D2 + DD + j] = tanhf(li * inv);
    }
}

// attend: tid<256 guarded math = bitwise round-4 attend_kernel; barriers full-block.
__device__ void attend_stage(const Params& p, float* __restrict__ z, int M,
                             int bid, int gdim, int tid, float* sm) {
    float* red  = sm;
    float* s_sc = sm + 512;
    for (int v = bid; v < NTOK; v += gdim) {
        float q0 = 0.f, q1 = 0.f;
        if (tid < 256) {
#pragma unroll
            for (int s = 0; s < SPLIT; ++s) {
                q0 += p.QP[((size_t)s * NTOK + v) * DD + tid];
                q1 += p.QP[((size_t)s * NTOK + v) * DD + 256 + tid];
            }
            q0 += p.qb[tid];
            q1 += p.qb[256 + tid];
        }
        for (int m = 0; m < M; ++m) {
            const float* K = p.Kmem + (size_t)m * NTOK * DD + (size_t)v * DD;
            __syncthreads();
            if (tid < 256) red[tid] = q0 * K[tid] + q1 * K[256 + tid];
            __syncthreads();
            for (int off = 128; off > 0; off >>= 1) {
                if (tid < off) red[tid] += red[tid + off];
                __syncthreads();
            }
            if (tid == 0) s_sc[m] = red[0] * SCALE * p.conf[v];
            __syncthreads();
        }
        if (tid == 0) {
            float mx = s_sc[0];
            for (int m = 1; m < M; ++m) mx = fmaxf(mx, s_sc[m]);
            float w[8], sum = 0.f;
            for (int m = 0; m < M; ++m) { w[m] = expf(s_sc[m] - mx); sum += w[m]; }
            for (int m = 0; m < M; ++m) s_sc[m] = w[m] / sum;
        }
        __syncthreads();
#pragma unroll
        for (int r = 0; r < 2; ++r) {
            int e = r * 512 + tid;
            float ctx = 0.f;
            for (int m = 0; m < M; ++m)
                ctx += s_sc[m] * p.Vmem[(size_t)m * NTOK * D2 + (size_t)v * D2 + e];
            z[(size_t)v * D2 + e] += 0.1f * ctx;
        }
    }
}

// finish: transcription of round-4's 512-thread finish_kernel (bitwise).
__device__ void finish_stage(const Params& p, float* __restrict__ z,
                             int bid, int gdim, int tid, float* sm) {
    float* s_z   = sm;                     // 1024
    float* s_red = sm + 1024;              // 512
    int*   s_idx = (int*)(sm + 1536);      // 512
    float* s_pd  = sm + 2048;              // 256
    float* s_pc  = sm + 2304;              // 256
    float* s_res = sm + 2560;              // 4
    int*   s_si  = (int*)(sm + 2564);

    for (int t0 = bid; t0 < NTOK; t0 += gdim) {
        __syncthreads();
        if (tid < 256) ((float4*)s_z)[tid] = ((const float4*)(z + (size_t)t0 * D2))[tid];
        __syncthreads();

        // ||z||^2
        {
            float a = s_z[tid], b = s_z[512 + tid];
            s_red[tid] = a * a + b * b;
            __syncthreads();
            for (int off = 256; off > 0; off >>= 1) {
                if (tid < off) s_red[tid] += s_red[tid + off];
                __syncthreads();
            }
            if (tid == 0) s_res[0] = s_red[0];
            __syncthreads();
        }

        // sym distance + argmin (first-min tie-break)
        {
            float dot = 0.f;
#pragma unroll
            for (int s = 0; s < SPLIT; ++s)
                dot += p.symP[((size_t)s * NTOK + t0) * NSYM + tid];
            float d = (s_res[0] + p.snorm[tid]) - 2.f * dot;
            s_red[tid] = d; s_idx[tid] = tid;
            __syncthreads();
            for (int off = 256; off > 0; off >>= 1) {
                if (tid < off) {
                    float o = s_red[tid + off]; int oi = s_idx[tid + off];
                    if (o < s_red[tid] || (o == s_red[tid] && oi < s_idx[tid])) {
                        s_red[tid] = o; s_idx[tid] = oi;
                    }
                }
                __syncthreads();
            }
            if (tid == 0) { s_res[1] = s_red[0]; s_si[0] = s_idx[0]; }
            __syncthreads();
        }

        // conf, straight-through update, symErr
        {
            int si = s_si[0];
            if (tid == 0) p.conf[t0] = 1.0f / (1.0f + s_res[1]);
            const float* crow = p.sym + (size_t)si * D2;
            float errp = 0.f;
#pragma unroll
            for (int r = 0; r < 2; ++r) {
                int e = r * 512 + tid;
                float zf = s_z[e];
                float diff = crow[e] - zf;
                errp += diff * diff;
                float zn = zf + diff;      // zs = z + (c - z)
                s_z[e] = zn;
                z[(size_t)t0 * D2 + e] = zn;
            }
            s_red[tid] = errp;
            __syncthreads();
            for (int off = 256; off > 0; off >>= 1) {
                if (tid < off) s_red[tid] += s_red[tid + off];
                __syncthreads();
            }
            if (tid == 0) p.symErr[t0] += s_red[0];
            __syncthreads();
        }

        // ||zs||^2
        {
            float a = s_z[tid], b = s_z[512 + tid];
            s_red[tid] = a * a + b * b;
            __syncthreads();
            for (int off = 256; off > 0; off >>= 1) {
                if (tid < off) s_red[tid] += s_red[tid + off];
                __syncthreads();
            }
            if (tid == 0) s_res[2] = s_red[0];
            __syncthreads();
        }

        // con quantize: split-K partial dots (threads 0..255), combine, argmin
        if (tid < 256) {
            int c = tid & 63, sl = tid >> 6;
            float pd = 0.f, pc = 0.f;
            int k0 = sl * 256;
#pragma unroll 4
            for (int k = k0; k < k0 + 256; ++k) {
                float w = p.conT[(size_t)k * NCON + c];
                pd += w * s_z[k];
                pc += w * w;
            }
            s_pd[tid] = pd; s_pc[tid] = pc;
        }
        __syncthreads();
        if (tid < 64) {
            float dot = ((s_pd[tid] + s_pd[64 + tid]) + s_pd[128 + tid]) + s_pd[192 + tid];
            float cn2 = ((s_pc[tid] + s_pc[64 + tid]) + s_pc[128 + tid]) + s_pc[192 + tid];
            s_red[tid] = (s_res[2] + cn2) - 2.f * dot;
            s_idx[tid] = tid;
        }
        __syncthreads();
        for (int off = 32; off > 0; off >>= 1) {
            if (tid < off) {
                float o = s_red[tid + off]; int oi = s_idx[tid + off];
                if (o < s_red[tid] || (o == s_red[tid] && oi < s_idx[tid])) {
                    s_red[tid] = o; s_idx[tid] = oi;
                }
            }
            __syncthreads();
        }
        int ci0 = s_idx[0];
        __syncthreads();

        // conErr
        {
            const float* crow = p.con + (size_t)ci0 * D2;
            float pp = 0.f;
#pragma unroll
            for (int r = 0; r < 2; ++r) {
                int e = r * 512 + tid;
                float diff = crow[e] - s_z[e];
                pp += diff * diff;
            }
            s_red[tid] = pp;
            __syncthreads();
            for (int off = 256; off > 0; off >>= 1) {
                if (tid < off) s_red[tid] += s_red[tid + off];
                __syncthreads();
            }
            if (tid == 0) p.conErr[t0] += s_red[0];
            __syncthreads();
        }
    }
}

__global__ __launch_bounds__(BLOCK, 1) void mega_kernel(Params p) {
    __shared__ __align__(16) float sm[4352];    // 17408 B
    int bid = blockIdx.x, tid = threadIdx.x;
    const int gdim = gridDim.x;
    unsigned nb = 0;
    float* sX = sm;
    float* sW = sm + 2176;

    // ---------- setup ----------
    if (bid == gdim - 1 && tid < 256) { p.symErr[tid] = 0.f; p.conErr[tid] = 0.f; p.hist[tid] = 0; }
    for (int v = bid; v < NTOK; v += gdim) {
        float r = p.mag[(size_t)v * DD + tid], t = p.phase[(size_t)v * DD + tid];
        p.bufA[(size_t)v * D2 + tid]      = r * cosf(t);
        p.bufA[(size_t)v * D2 + DD + tid] = r * sinf(t);
    }
    for (int c = bid; c < NSYM; c += gdim) {
        __syncthreads();
        if (tid < 256) {
            float4 v = ((const float4*)(p.sym + (size_t)c * D2))[tid];
            sm[tid] = v.x * v.x + v.y * v.y + v.z * v.z + v.w * v.w;
        }
        __syncthreads();
        for (int off = 128; off > 0; off >>= 1) {
            if (tid < off) sm[tid] += sm[tid + off];
            __syncthreads();
        }
        if (tid == 0) p.snorm[c] = sm[0];
    }
    transpose_tiles(p.qw,    p.qwT,      DD,    D2, DD,    bid, gdim, tid, sm);
    transpose_tiles(p.kw,    p.KVT,      DD,    D2, 1536,  bid, gdim, tid, sm);
    transpose_tiles(p.vw,    p.KVT + DD, D2,    D2, 1536,  bid, gdim, tid, sm);
    transpose_tiles(p.sym,   p.symT,     NSYM,  D2, NSYM,  bid, gdim, tid, sm);
    transpose_tiles(p.dec_w, p.decT,     VOCAB, D2, VOCAB, bid, gdim, tid, sm);
    transpose_tiles(p.con,   p.conT,     NCON,  D2, NCON,  bid, gdim, tid, sm);
    buildcw(p.Wr, p.Wi, p.CW, bid, gdim, tid, sm);
    nb += 1; gbar(p.bar, nb * gdim);

    float* cur = p.bufA;
    float* oth = p.bufB;
    for (int d = 0; d < NDEPTH; ++d) {
        if (d == 0) {
            for (int i = bid * BLOCK + tid; i < BS_TOT; i += gdim * BLOCK)
                atomicAdd(&p.hist[p.x[i]], 1);
        } else {
            for (int w = bid; w < NTOK * 3; w += gdim) {
                int t = w / 3;
                int e = (w % 3) * 512 + tid;
                float v = 0.f;
#pragma unroll
                for (int s = 0; s < SPLIT; ++s)
                    v += p.kvP[((size_t)s * NTOK + t) * 1536 + e];
                if (e < DD) p.Kmem[((size_t)(d - 1) * NTOK + t) * DD + e] = v + p.kb[e];
                else        p.Vmem[((size_t)(d - 1) * NTOK + t) * D2 + (e - DD)] = v + p.vb[e - DD];
            }
        }
        gemm_tiles(p.CW, cur, p.cellP, D2, 16, bid, gdim, tid, sX, sW);
        nb += 1; gbar(p.bar, nb * gdim);

        cellepi_stage(p.cellP, oth, bid, gdim, tid);
        { float* t_ = cur; cur = oth; oth = t_; }
        nb += 1; gbar(p.bar, nb * gdim);

        if (d > 0) {
            gemm_tiles(p.qwT, cur, p.QP, DD, 8, bid, gdim, tid, sX, sW);
            nb += 1; gbar(p.bar, nb * gdim);
            attend_stage(p, cur, d, bid, gdim, tid, sm);
            nb += 1; gbar(p.bar, nb * gdim);
        }

        gemm_tiles(p.symT, cur, p.symP, NSYM, 8, bid, gdim, tid, sX, sW);
        nb += 1; gbar(p.bar, nb * gdim);

        finish_stage(p, cur, bid, gdim, tid, sm);
        nb += 1; gbar(p.bar, nb * gdim);

        if (d < NDEPTH - 1) {   // depth-5 K/V never attended
            gemm_tiles(p.KVT, cur, p.kvP, 1536, 24, bid, gdim, tid, sX, sW);
            nb += 1; gbar(p.bar, nb * gdim);
        }
    }

    for (int l = 0; l < NLOOK; ++l) {
        gemm_tiles(p.CW, cur, p.cellP, D2, 16, bid, gdim, tid, sX, sW);
        nb += 1; gbar(p.bar, nb * gdim);
        cellepi_stage(p.cellP, oth, bid, gdim, tid);
        { float* t_ = cur; cur = oth; oth = t_; }
        nb += 1; gbar(p.bar, nb * gdim);
    }

    gemm_tiles(p.decT, cur, p.decP, VOCAB, 4, bid, gdim, tid, sX, sW);
    nb += 1; gbar(p.bar, nb * gdim);

    for (int t = bid; t < NTOK; t += gdim) {
        if (tid < 256) {
            float v = 0.f;
#pragma unroll
            for (int s = 0; s < SPLIT; ++s)
                v += p.decP[((size_t)s * NTOK + t) * VOCAB + tid];
            p.rows[(size_t)t * VOCAB + tid] = v + p.dec_b[tid];
        }
    }
    nb += 1; gbar(p.bar, nb * gdim);

    // scatter
    for (int i = bid * BLOCK + tid; i < BS_TOT * 64; i += gdim * BLOCK) {
        int pos = i >> 6, lane = i & 63;
        int v = p.x[pos];
        ((float4*)(p.out + (size_t)pos * VOCAB))[lane] =
            ((const float4*)(p.rows + (size_t)v * VOCAB))[lane];
    }

    // losses (block 0; bitwise round-4 loss_kernel)
    if (bid == 0) {
        double* rs = (double*)sm;
        double* rc = rs + 256;
        __syncthreads();
        if (tid < 256) {
            rs[tid] = (double)p.hist[tid] * (double)p.symErr[tid];
            rc[tid] = (double)p.hist[tid] * (double)p.conErr[tid];
        }
        __syncthreads();
        for (int off = 128; off > 0; off >>= 1) {
            if (tid < off) { rs[tid] += rs[tid + off]; rc[tid] += rc[tid + off]; }
            __syncthreads();
        }
        if (tid == 0) {
            const double denom = (double)BS_TOT * (double)D2;
            p.out[(size_t)BS_TOT * VOCAB]     = (float)(1.25 * rs[0] / denom);
            p.out[(size_t)BS_TOT * VOCAB + 1] = (float)(1.25 * rc[0] / denom);
        }
    }
}

extern "C" void kernel_launch(void* const* d_in, const int* in_sizes, int n_in,
                              void* d_out, int out_size, void* d_ws, size_t ws_size,
                              hipStream_t stream) {
    Params p;
    p.x     = (const int*)  d_in[0];
    p.mag   = (const float*)d_in[1];
    p.phase = (const float*)d_in[2];
    p.Wr    = (const float*)d_in[3];
    p.Wi    = (const float*)d_in[4];
    p.qw    = (const float*)d_in[5];
    p.qb    = (const float*)d_in[6];
    p.kw    = (const float*)d_in[7];
    p.kb    = (const float*)d_in[8];
    p.vw    = (const float*)d_in[9];
    p.vb    = (const float*)d_in[10];
    p.dec_w = (const float*)d_in[11];
    p.dec_b = (const float*)d_in[12];
    p.sym   = (const float*)d_in[13];
    p.con   = (const float*)d_in[14];
    p.out   = (float*)d_out;

    p.bar = (unsigned*)d_ws;
    float* w = (float*)d_ws + 16;   // 64 B for barrier counter
    auto take = [&](size_t n) { float* r = w; w += n; return r; };
    p.bufA   = take((size_t)NTOK * D2);
    p.bufB   = take((size_t)NTOK * D2);
    p.Kmem   = take((size_t)NDEPTH * NTOK * DD);
    p.Vmem   = take((size_t)NDEPTH * NTOK * D2);
    p.rows   = take((size_t)NTOK * VOCAB);
    p.CW     = take((size_t)D2 * D2);
    p.qwT    = take((size_t)D2 * DD);
    p.KVT    = take((size_t)D2 * 1536);
    p.symT   = take((size_t)D2 * NSYM);
    p.decT   = take((size_t)D2 * VOCAB);
    p.conT   = take((size_t)D2 * NCON);
    p.cellP  = take((size_t)SPLIT * NTOK * D2);
    p.QP     = take((size_t)SPLIT * NTOK * DD);
    p.symP   = take((size_t)SPLIT * NTOK * NSYM);
    p.kvP    = take((size_t)SPLIT * NTOK * 1536);
    p.decP   = take((size_t)SPLIT * NTOK * VOCAB);
    p.snorm  = take(NSYM);
    p.conf   = take(NTOK);
    p.symErr = take(NTOK);
    p.conErr = take(NTOK);
    p.hist   = (int*)take(NTOK);

    // Clamp grid to guaranteed-co-resident block count (host-side query, capture-safe).
    int maxb = 0;
    hipError_t oe = hipOccupancyMaxActiveBlocksPerMultiprocessor(
        &maxb, (const void*)mega_kernel, BLOCK, 0);
    int grid = 256;
    if (oe == hipSuccess && maxb >= 1) {
        long cap = (long)maxb * 256;   // 256 CUs on MI355X
        if (cap < grid) grid = (int)cap;
    }

    hipMemsetAsync(p.bar, 0, 64, stream);
    mega_kernel<<<grid, BLOCK, 0, stream>>>(p);
}

// Round 7
// 2058.275 us; speedup vs baseline: 1.0770x; 1.0770x over previous
//
#include <hip/hip_runtime.h>
#include <math.h>

constexpr int DD    = 512;
constexpr int D2    = 1024;
constexpr int NTOK  = 256;
constexpr int NSYM  = 512;
constexpr int NCON  = 64;
constexpr int VOCAB = 256;
constexpr int BS_TOT = 16384;
constexpr int NDEPTH = 6;
constexpr int NLOOK  = 3;
constexpr float EPSF = 1e-8f;
constexpr float SCALE = 0.044194173824159216f; // 512^-0.5

struct P2 {
    const int* x;
    const float *mag, *phase, *Wr, *Wi, *qw, *qb, *kw, *kb, *vw, *vb, *dec_w, *dec_b, *sym, *con;
    float* out;
    float *WrT, *WiT, *qwT, *vwT, *symT, *decT, *conT, *snorm, *cnorm, *rows, *symErr, *conErr;
};

// ---------------- setup: transposes + code norms ----------------
__device__ void tposeB(const float* __restrict__ in, float* __restrict__ outp,
                       int R, int C, int ldo, int bid, int gdim, int tid, float* sm) {
    float (*t)[33] = (float(*)[33])sm;
    int xx = tid & 31, yy = tid >> 5;       // block 256: yy 0..7
    int tcx = C >> 5, total = tcx * (R >> 5);
    for (int tile = bid; tile < total; tile += gdim) {
        int c0 = (tile % tcx) * 32, r0 = (tile / tcx) * 32;
        __syncthreads();
#pragma unroll
        for (int i = 0; i < 32; i += 8)
            t[yy + i][xx] = in[(size_t)(r0 + yy + i) * C + c0 + xx];
        __syncthreads();
#pragma unroll
        for (int i = 0; i < 32; i += 8)
            outp[(size_t)(c0 + yy + i) * ldo + r0 + xx] = t[xx][yy + i];
    }
}

__global__ __launch_bounds__(256) void setup_kernel(P2 p) {
    __shared__ float sm[1100];
    int bid = blockIdx.x, tid = threadIdx.x, g = gridDim.x;
    tposeB(p.Wr,    p.WrT,  DD,    DD, DD,    bid, g, tid, sm);
    tposeB(p.Wi,    p.WiT,  DD,    DD, DD,    bid, g, tid, sm);
    tposeB(p.qw,    p.qwT,  DD,    D2, DD,    bid, g, tid, sm);
    tposeB(p.vw,    p.vwT,  D2,    D2, D2,    bid, g, tid, sm);
    tposeB(p.sym,   p.symT, NSYM,  D2, NSYM,  bid, g, tid, sm);
    tposeB(p.dec_w, p.decT, VOCAB, D2, VOCAB, bid, g, tid, sm);
    tposeB(p.con,   p.conT, NCON,  D2, NCON,  bid, g, tid, sm);
    for (int c = bid; c < NSYM; c += g) {
        __syncthreads();
        float4 v = ((const float4*)(p.sym + (size_t)c * D2))[tid];
        sm[tid] = v.x*v.x + v.y*v.y + v.z*v.z + v.w*v.w;
        __syncthreads();
        for (int off = 128; off; off >>= 1) { if (tid < off) sm[tid] += sm[tid + off]; __syncthreads(); }
        if (tid == 0) p.snorm[c] = sm[0];
    }
    for (int c = bid; c < NCON; c += g) {
        __syncthreads();
        float4 v = ((const float4*)(p.con + (size_t)c * D2))[tid];
        sm[tid] = v.x*v.x + v.y*v.y + v.z*v.z + v.w*v.w;
        __syncthreads();
        for (int off = 128; off; off >>= 1) { if (tid < off) sm[tid] += sm[tid + off]; __syncthreads(); }
        if (tid == 0) p.cnorm[c] = sm[0];
    }
}

// ---------------- per-token pipeline: 2 tokens per block, no grid sync ----------------
__device__ __forceinline__ float wsum64(float v) {
#pragma unroll
    for (int off = 32; off; off >>= 1) v += __shfl_xor(v, off, 64);
    return v;
}

// cell: zc (LDS, 2 tokens) -> zn. Thread j computes lr/li for both tokens.
__device__ void cell_fn(const P2& p, const float* zc, float* zn, int tid) {
    float ar0 = 0, ai0 = 0, ar1 = 0, ai1 = 0;
#pragma unroll 4
    for (int k = 0; k < DD; ++k) {
        float wr = p.WrT[(size_t)k * DD + tid];   // coalesced across lanes
        float wi = p.WiT[(size_t)k * DD + tid];
        float zr0 = zc[k],        zi0 = zc[DD + k];      // LDS broadcast
        float zr1 = zc[1024 + k], zi1 = zc[1536 + k];
        ar0 += wr * zr0; ar0 -= wi * zi0;
        ai0 += wr * zi0; ai0 += wi * zr0;
        ar1 += wr * zr1; ar1 -= wi * zi1;
        ai1 += wr * zi1; ai1 += wi * zr1;
    }
    {
        float m = sqrtf(ar0*ar0 + ai0*ai0 + EPSF);
        float inv = 1.0f / (1.0f + m);
        zn[tid] = tanhf(ar0 * inv); zn[DD + tid] = tanhf(ai0 * inv);
    }
    {
        float m = sqrtf(ar1*ar1 + ai1*ai1 + EPSF);
        float inv = 1.0f / (1.0f + m);
        zn[1024 + tid] = tanhf(ar1 * inv); zn[1536 + tid] = tanhf(ai1 * inv);
    }
}

__global__ __launch_bounds__(512, 1) void token_kernel(P2 p) {
    __shared__ __align__(16) float zb[2 * 2 * 1024];   // [parity][token][1024]
    __shared__ __align__(16) float Hm[5 * 2 * 1024];   // memory entries
    __shared__ float qs[2 * 512];
    __shared__ float us[2 * 1024];                     // u, then hbar
    __shared__ float red[512];
    __shared__ float wsum[16];
    __shared__ int   wmi[16];
    __shared__ float sc[2][8];
    __shared__ float res[8];
    __shared__ float confL[2];
    __shared__ float errAcc[4];
    __shared__ int   sidx[4];

    int tid = threadIdx.x;
    int lane = tid & 63, wv = tid >> 6;
    int t0 = blockIdx.x * 2;
    int kA = tid, kB = tid + 512;

    if (tid < 4) errAcc[tid] = 0.f;
    // embed
    {
        float r0 = p.mag[(size_t)t0 * DD + tid],       ph0 = p.phase[(size_t)t0 * DD + tid];
        float r1 = p.mag[(size_t)(t0+1) * DD + tid],   ph1 = p.phase[(size_t)(t0+1) * DD + tid];
        zb[tid] = r0 * cosf(ph0);        zb[DD + tid] = r0 * sinf(ph0);
        zb[1024 + tid] = r1 * cosf(ph1); zb[1536 + tid] = r1 * sinf(ph1);
    }
    int par = 0;
    __syncthreads();

    for (int d = 0; d < NDEPTH; ++d) {
        // ---- cell ----
        cell_fn(p, zb + par * 2048, zb + (par ^ 1) * 2048, tid);
        par ^= 1;
        __syncthreads();
        float* zc = zb + par * 2048;

        // ---- attend (d>0): score_m = (kw^T Q)·H_m + Q·kb ; ctx = vw·hbar + vb ----
        if (d > 0) {
            int M = d;
            // Q
            {
                float a0 = 0, a1 = 0;
#pragma unroll 4
                for (int k = 0; k < D2; ++k) {
                    float w = p.qwT[(size_t)k * DD + tid];
                    a0 += w * zc[k]; a1 += w * zc[1024 + k];
                }
                qs[tid] = a0 + p.qb[tid]; qs[512 + tid] = a1 + p.qb[tid];
            }
            __syncthreads();
            // Qkb scalars
            {
                float pa = wsum64(qs[tid] * p.kb[tid]);
                float pb = wsum64(qs[512 + tid] * p.kb[tid]);
                if (lane == 0) { wsum[wv] = pa; wsum[8 + wv] = pb; }
            }
            __syncthreads();
            if (tid < 2) { float s = 0; for (int w = 0; w < 8; ++w) s += wsum[tid * 8 + w]; res[tid] = s; }
            __syncthreads();
            // u = kw^T Q  (kw native row-major: coalesced)
            {
                float uA0 = 0, uA1 = 0, uB0 = 0, uB1 = 0;
#pragma unroll 4
                for (int j = 0; j < DD; ++j) {
                    float a = p.kw[(size_t)j * D2 + kA];
                    float b = p.kw[(size_t)j * D2 + kB];
                    float q0 = qs[j], q1 = qs[512 + j];
                    uA0 += a * q0; uA1 += a * q1; uB0 += b * q0; uB1 += b * q1;
                }
                us[kA] = uA0; us[kB] = uB0; us[1024 + kA] = uA1; us[1024 + kB] = uB1;
            }
            __syncthreads();
            // scores
            for (int m = 0; m < M; ++m) {
                const float* h0 = &Hm[(m * 2) * 1024];
                const float* h1 = &Hm[(m * 2 + 1) * 1024];
                float p0 = wsum64(us[kA] * h0[kA] + us[kB] * h0[kB]);
                float p1 = wsum64(us[1024 + kA] * h1[kA] + us[1024 + kB] * h1[kB]);
                if (lane == 0) { red[m * 16 + wv] = p0; red[m * 16 + 8 + wv] = p1; }
            }
            __syncthreads();
            if (tid < 2 * M) {
                int m = tid >> 1, t = tid & 1;
                float s = 0;
                for (int w = 0; w < 8; ++w) s += red[m * 16 + t * 8 + w];
                sc[t][m] = (s + res[t]) * SCALE * confL[t];
            }
            __syncthreads();
            if (tid < 2) {
                float mx = sc[tid][0];
                for (int m = 1; m < M; ++m) mx = fmaxf(mx, sc[tid][m]);
                float sum = 0;
                for (int m = 0; m < M; ++m) { sc[tid][m] = expf(sc[tid][m] - mx); sum += sc[tid][m]; }
                for (int m = 0; m < M; ++m) sc[tid][m] /= sum;
            }
            __syncthreads();
            // hbar into us
            {
                float hA0 = 0, hA1 = 0, hB0 = 0, hB1 = 0;
                for (int m = 0; m < M; ++m) {
                    hA0 += sc[0][m] * Hm[(m * 2) * 1024 + kA];
                    hB0 += sc[0][m] * Hm[(m * 2) * 1024 + kB];
                    hA1 += sc[1][m] * Hm[(m * 2 + 1) * 1024 + kA];
                    hB1 += sc[1][m] * Hm[(m * 2 + 1) * 1024 + kB];
                }
                __syncthreads();
                us[kA] = hA0; us[kB] = hB0; us[1024 + kA] = hA1; us[1024 + kB] = hB1;
            }
            __syncthreads();
            // ctx and z update
            {
                float cA0 = 0, cA1 = 0, cB0 = 0, cB1 = 0;
#pragma unroll 4
                for (int k = 0; k < D2; ++k) {
                    float a = p.vwT[(size_t)k * D2 + kA];
                    float b = p.vwT[(size_t)k * D2 + kB];
                    float h0 = us[k], h1 = us[1024 + k];
                    cA0 += a * h0; cA1 += a * h1; cB0 += b * h0; cB1 += b * h1;
                }
                zc[kA] += 0.1f * (cA0 + p.vb[kA]);
                zc[kB] += 0.1f * (cB0 + p.vb[kB]);
                zc[1024 + kA] += 0.1f * (cA1 + p.vb[kA]);
                zc[1024 + kB] += 0.1f * (cB1 + p.vb[kB]);
            }
            __syncthreads();
        }

        // ---- sym quantize ----
        {
            float n0 = wsum64(zc[tid] * zc[tid] + zc[512 + tid] * zc[512 + tid]);
            float n1 = wsum64(zc[1024 + tid] * zc[1024 + tid] + zc[1536 + tid] * zc[1536 + tid]);
            if (lane == 0) { wsum[wv] = n0; wsum[8 + wv] = n1; }
        }
        __syncthreads();
        if (tid < 2) { float s = 0; for (int w = 0; w < 8; ++w) s += wsum[tid * 8 + w]; res[2 + tid] = s; }
        __syncthreads();
        {
            float dA = 0, dB = 0;
#pragma unroll 4
            for (int k = 0; k < D2; ++k) {
                float s = p.symT[(size_t)k * NSYM + tid];
                dA += s * zc[k]; dB += s * zc[1024 + k];
            }
            float v0 = res[2] + p.snorm[tid] - 2.f * dA; int i0 = tid;
            float v1 = res[3] + p.snorm[tid] - 2.f * dB; int i1 = tid;
#pragma unroll
            for (int off = 1; off < 64; off <<= 1) {
                float o0 = __shfl_xor(v0, off, 64); int oi0 = __shfl_xor(i0, off, 64);
                if (o0 < v0 || (o0 == v0 && oi0 < i0)) { v0 = o0; i0 = oi0; }
                float o1 = __shfl_xor(v1, off, 64); int oi1 = __shfl_xor(i1, off, 64);
                if (o1 < v1 || (o1 == v1 && oi1 < i1)) { v1 = o1; i1 = oi1; }
            }
            if (lane == 0) { wsum[wv] = v0; wmi[wv] = i0; wsum[8 + wv] = v1; wmi[8 + wv] = i1; }
        }
        __syncthreads();
        if (tid < 2) {
            float bv = wsum[tid * 8]; int bi = wmi[tid * 8];
            for (int w = 1; w < 8; ++w) {
                float o = wsum[tid * 8 + w]; int oi = wmi[tid * 8 + w];
                if (o < bv || (o == bv && oi < bi)) { bv = o; bi = oi; }
            }
            sidx[tid] = bi;
            confL[tid] = 1.0f / (1.0f + bv);
        }
        __syncthreads();
        {
            const float* r0 = p.sym + (size_t)sidx[0] * D2;
            const float* r1 = p.sym + (size_t)sidx[1] * D2;
            float d0A = r0[kA] - zc[kA],        d0B = r0[kB] - zc[kB];
            float d1A = r1[kA] - zc[1024 + kA], d1B = r1[kB] - zc[1024 + kB];
            zc[kA] += d0A; zc[kB] += d0B;           // straight-through: z + (c - z)
            zc[1024 + kA] += d1A; zc[1024 + kB] += d1B;
            float e0 = wsum64(d0A * d0A + d0B * d0B);
            float e1 = wsum64(d1A * d1A + d1B * d1B);
            if (lane == 0) { wsum[wv] = e0; wsum[8 + wv] = e1; }
        }
        __syncthreads();
        if (tid < 2) { float s = 0; for (int w = 0; w < 8; ++w) s += wsum[tid * 8 + w]; errAcc[tid] += s; }
        if (d < NDEPTH - 1) {   // store mem entry (depth-5 entry never attended)
            Hm[(d * 2) * 1024 + kA] = zc[kA];  Hm[(d * 2) * 1024 + kB] = zc[kB];
            Hm[(d * 2 + 1) * 1024 + kA] = zc[1024 + kA]; Hm[(d * 2 + 1) * 1024 + kB] = zc[1024 + kB];
        }
        __syncthreads();

        // ---- con quantize (loss only) ----
        {
            float m0 = wsum64(zc[tid] * zc[tid] + zc[512 + tid] * zc[512 + tid]);
            float m1 = wsum64(zc[1024 + tid] * zc[1024 + tid] + zc[1536 + tid] * zc[1536 + tid]);
            if (lane == 0) { wsum[wv] = m0; wsum[8 + wv] = m1; }
        }
        __syncthreads();
        if (tid < 2) { float s = 0; for (int w = 0; w < 8; ++w) s += wsum[tid * 8 + w]; res[4 + tid] = s; }
        __syncthreads();
        for (int t = 0; t < 2; ++t) {
            int c = tid & 63, s8 = tid >> 6;
            float pd = 0; int k0 = s8 * 128;
#pragma unroll 4
            for (int k = k0; k < k0 + 128; ++k)
                pd += p.conT[(size_t)k * NCON + c] * zc[t * 1024 + k];
            red[tid] = pd;
            __syncthreads();
            if (tid < 64) {
                float dot = 0;
                for (int s = 0; s < 8; ++s) dot += red[s * 64 + tid];
                float v = res[4 + t] + p.cnorm[tid] - 2.f * dot; int i = tid;
#pragma unroll
                for (int off = 1; off < 64; off <<= 1) {
                    float o = __shfl_xor(v, off, 64); int oi = __shfl_xor(i, off, 64);
                    if (o < v || (o == v && oi < i)) { v = o; i = oi; }
                }
                if (tid == 0) sidx[2] = i;
            }
            __syncthreads();
            const float* crow = p.con + (size_t)sidx[2] * D2;
            float dA = crow[kA] - zc[t * 1024 + kA];
            float dB = crow[kB] - zc[t * 1024 + kB];
            float e = wsum64(dA * dA + dB * dB);
            if (lane == 0) wsum[wv] = e;
            __syncthreads();
            if (tid == 0) { float s = 0; for (int w = 0; w < 8; ++w) s += wsum[w]; errAcc[2 + t] += s; }
            __syncthreads();
        }
    }

    // ---- look cells ----
    for (int l = 0; l < NLOOK; ++l) {
        cell_fn(p, zb + par * 2048, zb + (par ^ 1) * 2048, tid);
        par ^= 1;
        __syncthreads();
    }
    float* zc = zb + par * 2048;

    // ---- decode ----
    for (int t = 0; t < 2; ++t) {
        int j = tid & 255, h = tid >> 8;
        float acc = 0; int k0 = h * 512;
#pragma unroll 4
        for (int k = k0; k < k0 + 512; ++k)
            acc += p.decT[(size_t)k * VOCAB + j] * zc[t * 1024 + k];
        red[tid] = acc;
        __syncthreads();
        if (tid < 256)
            p.rows[(size_t)(t0 + t) * VOCAB + tid] = red[tid] + red[256 + tid] + p.dec_b[tid];
        __syncthreads();
    }
    if (tid < 2) { p.symErr[t0 + tid] = errAcc[tid]; p.conErr[t0 + tid] = errAcc[2 + tid]; }
}

// ---------------- scatter + loss ----------------
__global__ __launch_bounds__(256) void scatter_loss_kernel(P2 p) {
    int tid = threadIdx.x, bid = blockIdx.x;
    if (bid == 255) {
        __shared__ int h[256];
        __shared__ double rs[256], rc[256];
        h[tid] = 0;
        __syncthreads();
        for (int i = tid; i < BS_TOT; i += 256) atomicAdd(&h[p.x[i]], 1);
        __syncthreads();
        rs[tid] = (double)h[tid] * (double)p.symErr[tid];
        rc[tid] = (double)h[tid] * (double)p.conErr[tid];
        __syncthreads();
        for (int off = 128; off; off >>= 1) {
            if (tid < off) { rs[tid] += rs[tid + off]; rc[tid] += rc[tid + off]; }
            __syncthreads();
        }
        if (tid == 0) {
            const double denom = (double)BS_TOT * (double)D2;
            p.out[(size_t)BS_TOT * VOCAB]     = (float)(1.25 * rs[0] / denom);
            p.out[(size_t)BS_TOT * VOCAB + 1] = (float)(1.25 * rc[0] / denom);
        }
    } else {
        for (size_t i = (size_t)bid * 256 + tid; i < (size_t)BS_TOT * 64; i += (size_t)255 * 256) {
            int pos = (int)(i >> 6), lane = (int)(i & 63);
            ((float4*)(p.out + (size_t)pos * VOCAB))[lane] =
                ((const float4*)(p.rows + (size_t)p.x[pos] * VOCAB))[lane];
        }
    }
}

// ---------------- host ----------------
extern "C" void kernel_launch(void* const* d_in, const int* in_sizes, int n_in,
                              void* d_out, int out_size, void* d_ws, size_t ws_size,
                              hipStream_t stream) {
    P2 p;
    p.x     = (const int*)  d_in[0];
    p.mag   = (const float*)d_in[1];
    p.phase = (const float*)d_in[2];
    p.Wr    = (const float*)d_in[3];
    p.Wi    = (const float*)d_in[4];
    p.qw    = (const float*)d_in[5];
    p.qb    = (const float*)d_in[6];
    p.kw    = (const float*)d_in[7];
    p.kb    = (const float*)d_in[8];
    p.vw    = (const float*)d_in[9];
    p.vb    = (const float*)d_in[10];
    p.dec_w = (const float*)d_in[11];
    p.dec_b = (const float*)d_in[12];
    p.sym   = (const float*)d_in[13];
    p.con   = (const float*)d_in[14];
    p.out   = (float*)d_out;

    float* w = (float*)d_ws;
    auto take = [&](size_t n) { float* r = w; w += n; return r; };
    p.WrT    = take((size_t)DD * DD);
    p.WiT    = take((size_t)DD * DD);
    p.qwT    = take((size_t)D2 * DD);
    p.vwT    = take((size_t)D2 * D2);
    p.symT   = take((size_t)D2 * NSYM);
    p.decT   = take((size_t)D2 * VOCAB);
    p.conT   = take((size_t)D2 * NCON);
    p.snorm  = take(NSYM);
    p.cnorm  = take(NCON);
    p.rows   = take((size_t)NTOK * VOCAB);
    p.symErr = take(NTOK);
    p.conErr = take(NTOK);

    setup_kernel<<<256, 256, 0, stream>>>(p);
    token_kernel<<<NTOK / 2, 512, 0, stream>>>(p);
    scatter_loss_kernel<<<256, 256, 0, stream>>>(p);
}